// Round 2
// baseline (684.682 us; speedup 1.0000x reference)
//
#include <hip/hip_runtime.h>

#define T_LEN 1024
#define P_DIM 32
#define HOME_IDX 0
// finfo(f32).min/4 ; exact value irrelevant (never propagates to outputs),
// only needs NEG + A == NEG (ulp ~1e31 >> 0.01) and NEG << any finite delta.
#define NEGC (-(3.40282346638528859812e38f / 4.0f))

// One wave (64 threads) per batch, NO barriers (same-wave DS ordering).
// Lanes: p = lane&31 (state, replicated in both halves), h = lane>>5
// (half h scans predecessors q in [16h, 16h+16)).
// Forward also builds composed backtrack jump tables:
//   spsi[i] : state at time i+1 -> time i      (1 step)
//   sj2[i]  = spsi[i-1] o spsi[i]  (2 steps, valid i>=1)
//   sj4[i]  = sj2[i-2]  o sj2[i]   (4 steps, valid i>=4)
// Backtrack: 255 dependent reads via sj4, then parallel recovery of the
// skipped times via sj2 / spsi gathers across all 64 lanes.
__launch_bounds__(64, 1)
__global__ void crf_viterbi_kernel(const float* __restrict__ U,
                                   const float* __restrict__ A,
                                   const float* __restrict__ bias,
                                   int* __restrict__ out)
{
    __shared__ __align__(16) float sdelta[P_DIM];
    __shared__ unsigned char spsi[(T_LEN - 1) * P_DIM];
    __shared__ unsigned char sj2 [(T_LEN - 1) * P_DIM];
    __shared__ unsigned char sj4 [(T_LEN - 1) * P_DIM];
    __shared__ unsigned char spath[T_LEN];

    const int b     = blockIdx.x;
    const int lane  = threadIdx.x;
    const int p     = lane & 31;
    const int h     = lane >> 5;
    const int hbase = h << 4;

    // A fragment for this lane's half: A[q][p], q = hbase + j
    float Areg[16];
#pragma unroll
    for (int j = 0; j < 16; ++j)
        Areg[j] = A[(hbase + j) * P_DIM + p];
    const float A0p   = A[p];                            // A[HOME][p]
    const float A00   = A[HOME_IDX * P_DIM + HOME_IDX];  // A[HOME][HOME]
    const float biasp = bias[p];

    const float* __restrict__ Ub = U + (size_t)b * T_LEN * P_DIM;

    // t = 0
    float u0      = Ub[p] + biasp;
    float delta1  = (p == HOME_IDX) ? NEGC : u0;  // v=1 slice
    float delta0h = __shfl(u0, 0);                // v=0 slice lives only at HOME
    sdelta[p] = delta1;

    // 4-deep unary prefetch (bias folded; exact: reference adds bias once up front)
    float ubuf[4];
#pragma unroll
    for (int k = 0; k < 4; ++k)
        ubuf[k] = Ub[(1 + k) * P_DIM + p] + biasp;

    for (int tt = 1; tt < T_LEN; tt += 4) {
#pragma unroll
        for (int k = 0; k < 4; ++k) {
            const int t = tt + k;
            if (t < T_LEN) {
                const float u_cur = ubuf[k];

                // delta[q] for this half's q's: LDS round-trip, no barrier
                float c[16];
#pragma unroll
                for (int jj = 0; jj < 4; ++jj) {
                    float4 d4 = *reinterpret_cast<const float4*>(&sdelta[hbase + 4 * jj]);
                    c[4 * jj + 0] = d4.x + Areg[4 * jj + 0];
                    c[4 * jj + 1] = d4.y + Areg[4 * jj + 1];
                    c[4 * jj + 2] = d4.z + Areg[4 * jj + 2];
                    c[4 * jj + 3] = d4.w + Areg[4 * jj + 3];
                }

                // log-depth tournament, first (smallest) index wins ties
                float v8[8]; int i8[8];
#pragma unroll
                for (int j = 0; j < 8; ++j) {
                    bool g = c[2 * j + 1] > c[2 * j];
                    v8[j] = g ? c[2 * j + 1] : c[2 * j];
                    i8[j] = g ? (2 * j + 1) : (2 * j);
                }
                float v4[4]; int i4[4];
#pragma unroll
                for (int j = 0; j < 4; ++j) {
                    bool g = v8[2 * j + 1] > v8[2 * j];
                    v4[j] = g ? v8[2 * j + 1] : v8[2 * j];
                    i4[j] = g ? i8[2 * j + 1] : i8[2 * j];
                }
                float v2[2]; int i2[2];
#pragma unroll
                for (int j = 0; j < 2; ++j) {
                    bool g = v4[2 * j + 1] > v4[2 * j];
                    v2[j] = g ? v4[2 * j + 1] : v4[2 * j];
                    i2[j] = g ? i4[2 * j + 1] : i4[2 * j];
                }
                bool  g1 = v2[1] > v2[0];
                float bv = g1 ? v2[1] : v2[0];
                int   bj = g1 ? i2[1] : i2[0];
                int   aq = hbase + bj;

                // cross-half combine: half0 covers q<16 -> wins ties
                float ov = __shfl_xor(bv, 32);
                int   oq = __shfl_xor(aq, 32);
                bool  take = h ? (ov >= bv) : (ov > bv);
                float v1 = take ? ov : bv;
                int   a1 = take ? oq : aq;

                float v0   = delta0h + A0p;   // only q=HOME survives in v=0 slice
                bool  use1 = v1 > v0;          // strict, matches reference
                float bval = use1 ? v1 : v0;
                int   bq   = use1 ? a1 : 0;    // a0 == 0 exactly
                int   bvv  = use1 ? 1 : 0;

                bool  home = (p == HOME_IDX);
                float sel  = home ? v1 : bval;
                int   p1   = home ? a1 : bq;
                int   vv1  = home ? 1 : bvv;

                float dn1 = sel + u_cur;

                float ut0 = __shfl(u_cur, 0);          // U[t,HOME]+bias[HOME]
                delta0h = (delta0h + A00) + ut0;       // exact op order

                sdelta[p] = dn1;   // after this iter's reads: in-order DS pipe
                delta1    = dn1;

                const int i    = t - 1;
                const int psib = p1 | (vv1 << 5);
                spsi[i * P_DIM + p] = (unsigned char)psib;

                // jump2: compose with previous step (integer-only, exact)
                int im1 = (i >= 1) ? (i - 1) : 0;
                int g2  = spsi[im1 * P_DIM + p1];
                int b2  = vv1 ? g2 : 0;
                sj2[i * P_DIM + p] = (unsigned char)b2;

                // jump4: compose two jump2's
                int a2  = b2 & 31;
                int w2  = b2 >> 5;
                int im2 = (i >= 2) ? (i - 2) : 0;
                int g4  = sj2[im2 * P_DIM + a2];
                int b4  = w2 ? g4 : 0;
                sj4[i * P_DIM + p] = (unsigned char)b4;

                // refill prefetch slot (clamped address, value unused past end)
                int tp = t + 4; if (tp > T_LEN - 1) tp = T_LEN - 1;
                ubuf[k] = Ub[tp * P_DIM + p] + biasp;
            }
        }
    }

    // last_p = argmax_p delta_T[:,1], first index wins (lexicographic butterfly)
    float mv = delta1;
    int   mi = p;
#pragma unroll
    for (int m = 16; m >= 1; m >>= 1) {
        float ovv = __shfl_xor(mv, m);
        int   oii = __shfl_xor(mi, m);
        bool  tk = (ovv > mv) || ((ovv == mv) && (oii < mi));
        mv = tk ? ovv : mv;
        mi = tk ? oii : mi;
    }
    const int last_p = mi;

    // serial chase in 4-step jumps: times 1023, 1019, ..., 3, then 1
    if (lane == 0) {
        int y = last_p, v = 1;
        spath[T_LEN - 1] = (unsigned char)(y | (v << 5));
        for (int tau = T_LEN - 1; tau >= 7; tau -= 4) {
            int byte = v ? sj4[(tau - 1) * P_DIM + y] : 0;
            y = byte & 31;
            v = byte >> 5;
            spath[tau - 4] = (unsigned char)byte;
        }
        // y,v now at time 3: one jump2 to time 1
        int byte = v ? sj2[2 * P_DIM + y] : 0;
        spath[1] = (unsigned char)byte;
    }

    // recovery level A (parallel): tau ≡ 1 (mod 4), tau in [5, 1021]
#pragma unroll
    for (int r = 0; r < 4; ++r) {
        int idx = r * 64 + lane;
        if (idx < 255) {
            int tau = 5 + 4 * idx;
            int s   = spath[tau + 2];
            int yy  = s & 31, vv = s >> 5;
            int byte = vv ? sj2[(tau + 1) * P_DIM + yy] : 0;
            spath[tau] = (unsigned char)byte;
        }
    }
    // recovery level B (parallel): even tau in [0, 1022]
#pragma unroll
    for (int r = 0; r < 8; ++r) {
        int idx = r * 64 + lane;
        int tau = 2 * idx;
        int s   = spath[tau + 1];
        int yy  = s & 31, vv = s >> 5;
        int byte = vv ? spsi[tau * P_DIM + yy] : 0;
        spath[tau] = (unsigned char)byte;
    }

    // coalesced output
    int* __restrict__ outb = out + (size_t)b * T_LEN;
#pragma unroll
    for (int r = 0; r < 16; ++r) {
        int idx = r * 64 + lane;
        outb[idx] = spath[idx] & 31;
    }
}

extern "C" void kernel_launch(void* const* d_in, const int* in_sizes, int n_in,
                              void* d_out, int out_size, void* d_ws, size_t ws_size,
                              hipStream_t stream) {
    const float* U    = (const float*)d_in[0];   // (B, T, P) f32
    const float* A    = (const float*)d_in[1];   // (P, P)    f32
    const float* bias = (const float*)d_in[2];   // (P,)      f32
    int* out = (int*)d_out;                      // (B, T)    int32

    const int B = in_sizes[0] / (T_LEN * P_DIM);
    crf_viterbi_kernel<<<B, 64, 0, stream>>>(U, A, bias, out);
}

// Round 3
// 538.337 us; speedup vs baseline: 1.2718x; 1.2718x over previous
//
#include <hip/hip_runtime.h>

#define T_LEN 1024
#define P_DIM 32
// finfo(f32).min/4 = -(2^126 - 2^102); ulp = 2^102 >> |A|<=0.01, so NEG+A == NEG
// exactly, and NEG < any finite delta. The v=0 slice collapses to one scalar.
#define NEGC (-(3.40282346638528859812e38f / 4.0f))

// packed byte layout: entry (i,p) at ((i>>2)<<7) | (p<<2) | (i&3)
#define PSI_ADDR(i, p) ((((i) >> 2) << 7) | ((p) << 2) | ((i) & 3))

__device__ __forceinline__ float bperm_f(int addr, float v) {
    return __int_as_float(__builtin_amdgcn_ds_bpermute(addr, __float_as_int(v)));
}
__device__ __forceinline__ int bperm_i(int addr, int v) {
    return __builtin_amdgcn_ds_bpermute(addr, v);
}

// One wave per batch. Lanes: p = lane&31 (state), h = lane>>5 (half h scans
// predecessors q in [16h,16h+16)). delta1 lives in REGISTERS; predecessor
// broadcast via 16 independent ds_bpermute (one pipelined latency, no LDS
// round-trip). Value recurrence (fmax tree) is the only dependence chain;
// argmax recovered off-path via equality mask + ffs (exact first-index-wins,
// matching jnp.argmax). Backtrack: psi packed in LDS, binary-lifting tables
// j2/j4/j8 built AFTER the forward pass in parallel; lane-0 chase does 127
// dependent reads, then 3 parallel recovery levels.
__launch_bounds__(64, 1)
__global__ void crf_viterbi_kernel(const float* __restrict__ U,
                                   const float* __restrict__ A,
                                   const float* __restrict__ bias,
                                   int* __restrict__ out)
{
    __shared__ unsigned char spsi[32768];
    __shared__ unsigned char sj2[32768];
    __shared__ unsigned char sj4[32768];
    __shared__ unsigned char sj8[32768];
    __shared__ unsigned char spath[T_LEN];

    const int b     = blockIdx.x;
    const int lane  = threadIdx.x;
    const int p     = lane & 31;
    const int h     = lane >> 5;
    const int hbase = h << 4;
    const int qaddr = hbase << 2;        // byte addr of this half's first source lane
    const int xaddr = (lane ^ 32) << 2;  // cross-half partner
    const int zaddr = 0;                 // lane 0 (home broadcast)

    float Areg[16];
#pragma unroll
    for (int j = 0; j < 16; ++j)
        Areg[j] = A[(hbase + j) * P_DIM + p];
    const float A0p   = A[p];   // A[HOME][p]
    const float A00   = A[0];   // A[HOME][HOME]
    const float biasp = bias[p];

    const float* __restrict__ Ub = U + (size_t)b * T_LEN * P_DIM;

    // t = 0
    float u0      = Ub[p] + biasp;
    float delta1  = (p == 0) ? NEGC : u0;   // v=1 slice (register, per-lane p)
    float delta0h = bperm_f(zaddr, u0);     // v=0 slice lives only at HOME

    // 8-deep unary prefetch (bias folded once, as reference does)
    float ubuf[8];
#pragma unroll
    for (int k = 0; k < 8; ++k)
        ubuf[k] = Ub[(1 + k) * P_DIM + p] + biasp;

    unsigned int pack = 0;  // psi bytes for 4 consecutive i, flushed as dword

    auto body = [&](int t, int k) {
        const float u_cur = ubuf[k];
        int tp = t + 8; if (tp > T_LEN - 1) tp = T_LEN - 1;
        ubuf[k] = Ub[tp * P_DIM + p] + biasp;  // refill (clamped; unused past end)

        // 16 independent register broadcasts of delta1[q], q = hbase + j
        float c[16];
#pragma unroll
        for (int j = 0; j < 16; ++j)
            c[j] = bperm_f(qaddr + 4 * j, delta1) + Areg[j];

        // value-only max tree (depth 4), then cross-half max
        float m8[8];
#pragma unroll
        for (int j = 0; j < 8; ++j) m8[j] = fmaxf(c[2 * j], c[2 * j + 1]);
        float m4[4];
#pragma unroll
        for (int j = 0; j < 4; ++j) m4[j] = fmaxf(m8[2 * j], m8[2 * j + 1]);
        float m2a = fmaxf(m4[0], m4[1]);
        float m2b = fmaxf(m4[2], m4[3]);
        float bv  = fmaxf(m2a, m2b);
        float ovv = bperm_f(xaddr, bv);
        float v1  = fmaxf(bv, ovv);

        // argmax off-path: first q with c[q] == v1 (exact jnp.argmax semantics)
        unsigned int msk = 0;
#pragma unroll
        for (int j = 0; j < 16; ++j)
            msk |= (c[j] == v1) ? (1u << j) : 0u;
        int first  = msk ? (hbase + (__ffs(msk) - 1)) : 99;
        int ofirst = bperm_i(xaddr, first);
        int a1     = min(first, ofirst);

        // v=0 slice: only q=HOME survives (NEG+A==NEG exactly); a0 == 0
        float v0   = delta0h + A0p;
        bool  use1 = v1 > v0;                 // strict, matches reference
        bool  home = (p == 0);
        bool  sel1 = home || use1;
        float sel  = sel1 ? v1 : v0;
        int   p1   = sel1 ? a1 : 0;
        int   vv1  = sel1 ? 1 : 0;
        float dn1  = sel + u_cur;

        float ut0 = bperm_f(zaddr, u_cur);    // U[t,HOME]+bias[HOME]
        delta0h = (delta0h + A00) + ut0;      // exact reference op order
        delta1  = dn1;

        const int i = t - 1;
        unsigned int psib = (unsigned int)(p1 | (vv1 << 5));
        pack |= psib << (8 * (i & 3));
        if ((i & 3) == 3) {
            if (h == 0)
                *reinterpret_cast<unsigned int*>(&spsi[((i >> 2) << 7) | (p << 2)]) = pack;
            pack = 0;
        }
    };

    // main loop: full groups of 8 (t = 1..1016), then tail t = 1017..1023
    for (int tt = 1; tt + 7 < T_LEN; tt += 8) {
#pragma unroll
        for (int k = 0; k < 8; ++k) body(tt + k, k);
    }
#pragma unroll
    for (int k = 0; k < 7; ++k) body(1017 + k, k);
    // flush partial psi dword (i = 1020..1022, group 255)
    if (h == 0)
        *reinterpret_cast<unsigned int*>(&spsi[(255 << 7) | (p << 2)]) = pack;

    // last_p = argmax_p delta_T[:,1], first index wins
    float mv = delta1;
    int   mi = p;
#pragma unroll
    for (int m = 16; m >= 1; m >>= 1) {
        float ov2 = __shfl_xor(mv, m);
        int   oi2 = __shfl_xor(mi, m);
        bool  tk  = (ov2 > mv) || ((ov2 == mv) && (oi2 < mi));
        mv = tk ? ov2 : mv;
        mi = tk ? oi2 : mi;
    }
    const int last_p = mi;

    // ---- parallel binary-lifting table builds (throughput-bound) ----
    // j2(i,p) = psi(i,p).v ? psi(i-1)[psi(i,p).p] : 0
#pragma unroll 2
    for (int r = 0; r < 512; ++r) {
        int idx = (r << 6) + lane;
        if (idx < 1023 * 32) {
            int i = idx >> 5, pp = idx & 31;
            int bb = spsi[PSI_ADDR(i, pp)];
            int p1 = bb & 31, v = bb >> 5;
            int im = (i >= 1) ? (i - 1) : 0;
            int g  = spsi[PSI_ADDR(im, p1)];
            sj2[PSI_ADDR(i, pp)] = (unsigned char)((v && i >= 1) ? g : 0);
        }
    }
    // j4 = j2 o j2 (shift 2)
#pragma unroll 2
    for (int r = 0; r < 512; ++r) {
        int idx = (r << 6) + lane;
        if (idx < 1023 * 32) {
            int i = idx >> 5, pp = idx & 31;
            int bb = sj2[PSI_ADDR(i, pp)];
            int aa = bb & 31, w = bb >> 5;
            int im = (i >= 2) ? (i - 2) : 0;
            int g  = sj2[PSI_ADDR(im, aa)];
            sj4[PSI_ADDR(i, pp)] = (unsigned char)(w ? g : 0);
        }
    }
    // j8 = j4 o j4 (shift 4)
#pragma unroll 2
    for (int r = 0; r < 512; ++r) {
        int idx = (r << 6) + lane;
        if (idx < 1023 * 32) {
            int i = idx >> 5, pp = idx & 31;
            int bb = sj4[PSI_ADDR(i, pp)];
            int aa = bb & 31, w = bb >> 5;
            int im = (i >= 4) ? (i - 4) : 0;
            int g  = sj4[PSI_ADDR(im, aa)];
            sj8[PSI_ADDR(i, pp)] = (unsigned char)(w ? g : 0);
        }
    }

    // ---- serial chase in 8-step jumps: anchors tau = 1023, 1015, ..., 7 ----
    if (lane == 0) {
        int y = last_p, v = 1;
        spath[T_LEN - 1] = (unsigned char)(y | (v << 5));
        for (int tau = T_LEN - 1; tau >= 15; tau -= 8) {
            int byte = v ? sj8[PSI_ADDR(tau - 1, y)] : 0;
            y = byte & 31; v = byte >> 5;
            spath[tau - 8] = (unsigned char)byte;
        }
    }

    // ---- parallel recovery ----
    // A: anchors tau ≡ 7 (mod 8) -> fill tau-4 (128 entries)
#pragma unroll
    for (int r = 0; r < 2; ++r) {
        int ii  = (r << 6) + lane;
        int tau = 7 + (ii << 3);
        int s   = spath[tau];
        int y   = s & 31, v = s >> 5;
        int byte = v ? sj4[PSI_ADDR(tau - 1, y)] : 0;
        spath[tau - 4] = (unsigned char)byte;
    }
    // B: known tau ≡ 3 (mod 4) -> fill tau-2 (256 entries)
#pragma unroll
    for (int r = 0; r < 4; ++r) {
        int ii  = (r << 6) + lane;
        int tau = 3 + (ii << 2);
        int s   = spath[tau];
        int y   = s & 31, v = s >> 5;
        int byte = v ? sj2[PSI_ADDR(tau - 1, y)] : 0;
        spath[tau - 2] = (unsigned char)byte;
    }
    // C: known odd tau -> fill tau-1 (512 entries)
#pragma unroll
    for (int r = 0; r < 8; ++r) {
        int ii  = (r << 6) + lane;
        int tau = 1 + (ii << 1);
        int s   = spath[tau];
        int y   = s & 31, v = s >> 5;
        int byte = v ? spsi[PSI_ADDR(tau - 1, y)] : 0;
        spath[tau - 1] = (unsigned char)byte;
    }

    // coalesced output
    int* __restrict__ outb = out + (size_t)b * T_LEN;
#pragma unroll
    for (int r = 0; r < 16; ++r) {
        int idx = (r << 6) + lane;
        outb[idx] = spath[idx] & 31;
    }
}

extern "C" void kernel_launch(void* const* d_in, const int* in_sizes, int n_in,
                              void* d_out, int out_size, void* d_ws, size_t ws_size,
                              hipStream_t stream) {
    const float* U    = (const float*)d_in[0];   // (B, T, P) f32
    const float* A    = (const float*)d_in[1];   // (P, P)    f32
    const float* bias = (const float*)d_in[2];   // (P,)      f32
    int* out = (int*)d_out;                      // (B, T)    int32

    const int B = in_sizes[0] / (T_LEN * P_DIM);
    crf_viterbi_kernel<<<B, 64, 0, stream>>>(U, A, bias, out);
}

// Round 4
// 533.849 us; speedup vs baseline: 1.2825x; 1.0084x over previous
//
#include <hip/hip_runtime.h>

#define T_LEN 1024
#define P_DIM 32
// finfo(f32).min/4 = -(2^126 - 2^102); ulp = 2^102 >> |A|<=0.01, so NEG+A == NEG
// exactly, and NEG < any finite delta. The v=0 slice collapses to one scalar.
#define NEGC (-(3.40282346638528859812e38f / 4.0f))

// packed byte layout: entry (i,p) at ((i>>2)<<7) | (p<<2) | (i&3)
#define PSI_ADDR(i, p) ((((i) >> 2) << 7) | ((p) << 2) | ((i) & 3))

__device__ __forceinline__ float bperm_f(int addr, float v) {
    return __int_as_float(__builtin_amdgcn_ds_bpermute(addr, __float_as_int(v)));
}
__device__ __forceinline__ int bperm_i(int addr, int v) {
    return __builtin_amdgcn_ds_bpermute(addr, v);
}

// One wave per batch. Lanes: p = lane&31 (state), h = lane>>5 (half h scans
// predecessors q in [16h,16h+16)). delta1 lives in REGISTERS; predecessor
// broadcast via 16 independent ds_bpermute. Value recurrence (fmax tree) is
// the only dependence chain; argmax recovered off-path via equality mask +
// ffs (exact first-index-wins, matching jnp.argmax).
//
// R4 change vs R3: unary prefetch loads are RAW (no fused +bias). The fused
// add forced s_waitcnt vmcnt(0) on a just-issued load -> ~700-900 cyc HBM
// stall per iteration (the common constant behind R1/R2/R3's ~1100 cyc/iter).
// Bias is added at consumption, 8 iterations after the load issues.
__launch_bounds__(64, 1)
__global__ void crf_viterbi_kernel(const float* __restrict__ U,
                                   const float* __restrict__ A,
                                   const float* __restrict__ bias,
                                   int* __restrict__ out)
{
    __shared__ unsigned char spsi[32768];
    __shared__ unsigned char sj2[32768];
    __shared__ unsigned char sj4[32768];
    __shared__ unsigned char sj8[32768];
    __shared__ unsigned char spath[T_LEN];

    const int b     = blockIdx.x;
    const int lane  = threadIdx.x;
    const int p     = lane & 31;
    const int h     = lane >> 5;
    const int hbase = h << 4;
    const int qaddr = hbase << 2;        // byte addr of this half's first source lane
    const int xaddr = (lane ^ 32) << 2;  // cross-half partner
    const int zaddr = 0;                 // lane 0 (home broadcast)

    float Areg[16];
#pragma unroll
    for (int j = 0; j < 16; ++j)
        Areg[j] = A[(hbase + j) * P_DIM + p];
    const float A0p   = A[p];   // A[HOME][p]
    const float A00   = A[0];   // A[HOME][HOME]
    const float biasp = bias[p];

    const float* __restrict__ Ub = U + (size_t)b * T_LEN * P_DIM;

    // t = 0
    float u0      = Ub[p] + biasp;
    float delta1  = (p == 0) ? NEGC : u0;   // v=1 slice (register, per-lane p)
    float delta0h = bperm_f(zaddr, u0);     // v=0 slice lives only at HOME

    // 8-deep unary prefetch — RAW values, bias added at consumption
    float ubuf[8];
#pragma unroll
    for (int k = 0; k < 8; ++k)
        ubuf[k] = Ub[(1 + k) * P_DIM + p];

    unsigned int pack = 0;  // psi bytes for 4 consecutive i, flushed as dword

    auto body = [&](int t, int k) {
        // consume slot k (its load was issued 8 iterations ago — vmcnt covered)
        const float u_cur = ubuf[k] + biasp;
        int tp = t + 8; if (tp > T_LEN - 1) tp = T_LEN - 1;
        ubuf[k] = Ub[tp * P_DIM + p];     // raw refill, no dependent use here

        // 16 independent register broadcasts of delta1[q], q = hbase + j
        float c[16];
#pragma unroll
        for (int j = 0; j < 16; ++j)
            c[j] = bperm_f(qaddr + 4 * j, delta1) + Areg[j];

        // value-only max tree (depth 4), then cross-half max
        float m8[8];
#pragma unroll
        for (int j = 0; j < 8; ++j) m8[j] = fmaxf(c[2 * j], c[2 * j + 1]);
        float m4[4];
#pragma unroll
        for (int j = 0; j < 4; ++j) m4[j] = fmaxf(m8[2 * j], m8[2 * j + 1]);
        float m2a = fmaxf(m4[0], m4[1]);
        float m2b = fmaxf(m4[2], m4[3]);
        float bv  = fmaxf(m2a, m2b);
        float ovv = bperm_f(xaddr, bv);
        float v1  = fmaxf(bv, ovv);

        // argmax off-path: first q with c[q] == v1 (exact jnp.argmax semantics)
        unsigned int msk = 0;
#pragma unroll
        for (int j = 0; j < 16; ++j)
            msk |= (c[j] == v1) ? (1u << j) : 0u;
        int first  = msk ? (hbase + (__ffs(msk) - 1)) : 99;
        int ofirst = bperm_i(xaddr, first);
        int a1     = min(first, ofirst);

        // v=0 slice: only q=HOME survives (NEG+A==NEG exactly); a0 == 0
        float v0   = delta0h + A0p;
        bool  use1 = v1 > v0;                 // strict, matches reference
        bool  home = (p == 0);
        bool  sel1 = home || use1;
        float sel  = sel1 ? v1 : v0;
        int   p1   = sel1 ? a1 : 0;
        int   vv1  = sel1 ? 1 : 0;
        float dn1  = sel + u_cur;

        float ut0 = bperm_f(zaddr, u_cur);    // U[t,HOME]+bias[HOME]
        delta0h = (delta0h + A00) + ut0;      // exact reference op order
        delta1  = dn1;

        const int i = t - 1;
        unsigned int psib = (unsigned int)(p1 | (vv1 << 5));
        pack |= psib << (8 * (i & 3));
        if ((i & 3) == 3) {
            if (h == 0)
                *reinterpret_cast<unsigned int*>(&spsi[((i >> 2) << 7) | (p << 2)]) = pack;
            pack = 0;
        }
    };

    // main loop: full groups of 8 (t = 1..1016), then tail t = 1017..1023
    for (int tt = 1; tt + 7 < T_LEN; tt += 8) {
#pragma unroll
        for (int k = 0; k < 8; ++k) body(tt + k, k);
    }
#pragma unroll
    for (int k = 0; k < 7; ++k) body(1017 + k, k);
    // flush partial psi dword (i = 1020..1022, group 255)
    if (h == 0)
        *reinterpret_cast<unsigned int*>(&spsi[(255 << 7) | (p << 2)]) = pack;

    // last_p = argmax_p delta_T[:,1], first index wins
    float mv = delta1;
    int   mi = p;
#pragma unroll
    for (int m = 16; m >= 1; m >>= 1) {
        float ov2 = __shfl_xor(mv, m);
        int   oi2 = __shfl_xor(mi, m);
        bool  tk  = (ov2 > mv) || ((ov2 == mv) && (oi2 < mi));
        mv = tk ? ov2 : mv;
        mi = tk ? oi2 : mi;
    }
    const int last_p = mi;

    // ---- parallel binary-lifting table builds (throughput-bound) ----
    // j2(i,p) = psi(i,p).v ? psi(i-1)[psi(i,p).p] : 0
#pragma unroll 2
    for (int r = 0; r < 512; ++r) {
        int idx = (r << 6) + lane;
        if (idx < 1023 * 32) {
            int i = idx >> 5, pp = idx & 31;
            int bb = spsi[PSI_ADDR(i, pp)];
            int p1 = bb & 31, v = bb >> 5;
            int im = (i >= 1) ? (i - 1) : 0;
            int g  = spsi[PSI_ADDR(im, p1)];
            sj2[PSI_ADDR(i, pp)] = (unsigned char)((v && i >= 1) ? g : 0);
        }
    }
    // j4 = j2 o j2 (shift 2)
#pragma unroll 2
    for (int r = 0; r < 512; ++r) {
        int idx = (r << 6) + lane;
        if (idx < 1023 * 32) {
            int i = idx >> 5, pp = idx & 31;
            int bb = sj2[PSI_ADDR(i, pp)];
            int aa = bb & 31, w = bb >> 5;
            int im = (i >= 2) ? (i - 2) : 0;
            int g  = sj2[PSI_ADDR(im, aa)];
            sj4[PSI_ADDR(i, pp)] = (unsigned char)(w ? g : 0);
        }
    }
    // j8 = j4 o j4 (shift 4)
#pragma unroll 2
    for (int r = 0; r < 512; ++r) {
        int idx = (r << 6) + lane;
        if (idx < 1023 * 32) {
            int i = idx >> 5, pp = idx & 31;
            int bb = sj4[PSI_ADDR(i, pp)];
            int aa = bb & 31, w = bb >> 5;
            int im = (i >= 4) ? (i - 4) : 0;
            int g  = sj4[PSI_ADDR(im, aa)];
            sj8[PSI_ADDR(i, pp)] = (unsigned char)(w ? g : 0);
        }
    }

    // ---- serial chase in 8-step jumps: anchors tau = 1023, 1015, ..., 7 ----
    if (lane == 0) {
        int y = last_p, v = 1;
        spath[T_LEN - 1] = (unsigned char)(y | (v << 5));
        for (int tau = T_LEN - 1; tau >= 15; tau -= 8) {
            int byte = v ? sj8[PSI_ADDR(tau - 1, y)] : 0;
            y = byte & 31; v = byte >> 5;
            spath[tau - 8] = (unsigned char)byte;
        }
    }

    // ---- parallel recovery ----
    // A: anchors tau ≡ 7 (mod 8) -> fill tau-4 (128 entries)
#pragma unroll
    for (int r = 0; r < 2; ++r) {
        int ii  = (r << 6) + lane;
        int tau = 7 + (ii << 3);
        int s   = spath[tau];
        int y   = s & 31, v = s >> 5;
        int byte = v ? sj4[PSI_ADDR(tau - 1, y)] : 0;
        spath[tau - 4] = (unsigned char)byte;
    }
    // B: known tau ≡ 3 (mod 4) -> fill tau-2 (256 entries)
#pragma unroll
    for (int r = 0; r < 4; ++r) {
        int ii  = (r << 6) + lane;
        int tau = 3 + (ii << 2);
        int s   = spath[tau];
        int y   = s & 31, v = s >> 5;
        int byte = v ? sj2[PSI_ADDR(tau - 1, y)] : 0;
        spath[tau - 2] = (unsigned char)byte;
    }
    // C: known odd tau -> fill tau-1 (512 entries)
#pragma unroll
    for (int r = 0; r < 8; ++r) {
        int ii  = (r << 6) + lane;
        int tau = 1 + (ii << 1);
        int s   = spath[tau];
        int y   = s & 31, v = s >> 5;
        int byte = v ? spsi[PSI_ADDR(tau - 1, y)] : 0;
        spath[tau - 1] = (unsigned char)byte;
    }

    // coalesced output
    int* __restrict__ outb = out + (size_t)b * T_LEN;
#pragma unroll
    for (int r = 0; r < 16; ++r) {
        int idx = (r << 6) + lane;
        outb[idx] = spath[idx] & 31;
    }
}

extern "C" void kernel_launch(void* const* d_in, const int* in_sizes, int n_in,
                              void* d_out, int out_size, void* d_ws, size_t ws_size,
                              hipStream_t stream) {
    const float* U    = (const float*)d_in[0];   // (B, T, P) f32
    const float* A    = (const float*)d_in[1];   // (P, P)    f32
    const float* bias = (const float*)d_in[2];   // (P,)      f32
    int* out = (int*)d_out;                      // (B, T)    int32

    const int B = in_sizes[0] / (T_LEN * P_DIM);
    crf_viterbi_kernel<<<B, 64, 0, stream>>>(U, A, bias, out);
}